// Round 2
// baseline (813.395 us; speedup 1.0000x reference)
//
#include <hip/hip_runtime.h>

// Volume renderer (NeRF-style) — thread-per-ray, LDS-tiled, BARRIER-FREE
// software pipeline.
//
// Key changes vs previous version (251 us, 2.5 TB/s, latency-bound):
//   - Blocks are ONE wave (64 threads). LDS is private to the wave, so NO
//     __syncthreads is needed at all: the compiler orders ds_write/ds_read
//     via lgkmcnt and global->reg loads via vmcnt. This removes the
//     structural `s_waitcnt vmcnt(0)` drain the barrier forced every tile.
//   - Depth-1 register prefetch (async-STAGE split): tile k+1's 10 float4
//     global loads are issued BEFORE tile k's compute; the vmcnt wait sits
//     at tile k+1's LDS commit, covered by tile k's compute. Each wave keeps
//     ~10 KB continuously in flight (~80 KB/CU >> BW*latency ~15 KB) =>
//     HBM-saturated instead of latency-bound.
//   - The per-tile strided d_carry gather (64 discrete cache lines per
//     instruction, the long pole of every drain) is GONE: a "pending sample"
//     register carry finishes each tile's last sample at the start of the
//     next tile, and sample 127 is finished after the loop with the 1e10
//     sentinel (exp(-1e10*sigma): correct even for sigma == 0).
//   - Serial per-ray recurrence keeps the reference cumprod order exactly.
//
// LDS rows padded to ODD float4 counts (3/3/7 quads) -> conflict-free b128.

#define FAR_DELTA 1e10f

__global__ __launch_bounds__(64) void volrender_kernel(
    const float* __restrict__ rgb,       // [N, 128, 3]
    const float* __restrict__ density,   // [N, 128, 1]
    const float* __restrict__ dist,      // [N, 128]
    float* __restrict__ out,             // [N, 3]
    int n_rays)
{
    const int t  = threadIdx.x;          // 0..63 — one wave per block
    const int r0 = blockIdx.x << 6;      // 64 rays per block

    __shared__ float SIG[64 * 12];       // density tile (8 floats used/row)
    __shared__ float DST[64 * 12];       // dist tile
    __shared__ float RGBT[64 * 28];      // rgb tile (24 floats used/row)

    // ---- per-lane staging addresses (fixed; advance by tile offset) -------
    // density/dist element j in {t, t+64}: row = j>>1, col = (j&1)*4
    const int r_a = t >> 1;            const int c_a = (t & 1) << 2;
    const int r_b = 32 + (t >> 1);     const int c_b = c_a;
    const int gra = min(r0 + r_a, n_rays - 1);
    const int grb = min(r0 + r_b, n_rays - 1);
    const float* sigpa = density + (size_t)gra * 128 + c_a;
    const float* sigpb = density + (size_t)grb * 128 + c_b;
    const float* dstpa = dist    + (size_t)gra * 128 + c_a;
    const float* dstpb = dist    + (size_t)grb * 128 + c_b;

    // rgb element j = t + 64k (k=0..5): row = j/6, col = (j%6)*4
    const float* rgbp[6];
    int rrow[6], rcol[6];
    #pragma unroll
    for (int k = 0; k < 6; ++k) {
        const int j   = t + (k << 6);
        const int row = j / 6;
        const int col = (j - row * 6) << 2;
        rrow[k] = row; rcol[k] = col;
        const int gr  = min(r0 + row, n_rays - 1);
        rgbp[k] = rgb + (size_t)gr * 384 + col;
    }

    float T = 1.0f, accR = 0.0f, accG = 0.0f, accB = 0.0f;
    // pending sample carry: sigma=0 => e=exp(0)=1 => w=0 for the dummy
    float sig_p = 0.0f, d_p = 0.0f, cr_p = 0.0f, cg_p = 0.0f, cb_p = 0.0f;

    // ---- pipeline stages ---------------------------------------------------
    auto issue = [&](float4* R, int s0) {          // global -> regs (async)
        R[0] = *(const float4*)(sigpa + s0);
        R[1] = *(const float4*)(sigpb + s0);
        R[2] = *(const float4*)(dstpa + s0);
        R[3] = *(const float4*)(dstpb + s0);
        #pragma unroll
        for (int k = 0; k < 6; ++k)
            R[4 + k] = *(const float4*)(rgbp[k] + s0 * 3);
    };
    auto commit = [&](const float4* R) {           // regs -> LDS (vmcnt wait here)
        *(float4*)&SIG[r_a * 12 + c_a] = R[0];
        *(float4*)&SIG[r_b * 12 + c_b] = R[1];
        *(float4*)&DST[r_a * 12 + c_a] = R[2];
        *(float4*)&DST[r_b * 12 + c_b] = R[3];
        #pragma unroll
        for (int k = 0; k < 6; ++k)
            *(float4*)&RGBT[rrow[k] * 28 + rcol[k]] = R[4 + k];
    };
    auto compute = [&](int s0) {                   // own-ray recurrence, 8 samples
        const float4 sg0 = *(const float4*)&SIG[t * 12];
        const float4 sg1 = *(const float4*)&SIG[t * 12 + 4];
        const float4 dv0 = *(const float4*)&DST[t * 12];
        const float4 dv1 = *(const float4*)&DST[t * 12 + 4];
        float cf[24];
        #pragma unroll
        for (int k = 0; k < 6; ++k) {
            const float4 v = *(const float4*)&RGBT[t * 28 + (k << 2)];
            cf[4*k] = v.x; cf[4*k+1] = v.y; cf[4*k+2] = v.z; cf[4*k+3] = v.w;
        }
        const float dl[8] = {dv0.x,dv0.y,dv0.z,dv0.w, dv1.x,dv1.y,dv1.z,dv1.w};
        const float sl[8] = {sg0.x,sg0.y,sg0.z,sg0.w, sg1.x,sg1.y,sg1.z,sg1.w};

        // finish the pending sample: its delta reaches into this tile
        {
            const float e = __expf(-sig_p * (dl[0] - d_p));
            const float w = T - T * e;
            T *= e;
            accR += w * cr_p; accG += w * cg_p; accB += w * cb_p;
        }
        #pragma unroll
        for (int j = 0; j < 7; ++j) {
            const float e = __expf(-sl[j] * (dl[j + 1] - dl[j]));
            const float w = T - T * e;
            T *= e;
            accR += w * cf[3*j + 0]; accG += w * cf[3*j + 1]; accB += w * cf[3*j + 2];
        }
        sig_p = sl[7]; d_p = dl[7];
        cr_p = cf[21]; cg_p = cf[22]; cb_p = cf[23];
        (void)s0;
    };

    // ---- main pipeline: commit(k) | issue(k+1) | compute(k) ---------------
    float4 A[10], B[10];
    issue(A, 0);
    #pragma unroll
    for (int kk = 0; kk < 8; ++kk) {
        // tile 2kk
        commit(A);
        issue(B, (2 * kk + 1) * 8);
        compute(2 * kk * 8);
        // tile 2kk+1
        commit(B);
        if (kk < 7) issue(A, (2 * kk + 2) * 8);
        compute((2 * kk + 1) * 8);
    }

    // sample 127: sentinel delta
    {
        const float e = __expf(-sig_p * FAR_DELTA);
        const float w = T - T * e;
        accR += w * cr_p; accG += w * cg_p; accB += w * cb_p;
    }

    if (r0 + t < n_rays) {
        float* o = out + (size_t)(r0 + t) * 3;
        o[0] = accR;
        o[1] = accG;
        o[2] = accB;
    }
}

extern "C" void kernel_launch(void* const* d_in, const int* in_sizes, int n_in,
                              void* d_out, int out_size, void* d_ws, size_t ws_size,
                              hipStream_t stream) {
    const float* rgb     = (const float*)d_in[0];
    const float* density = (const float*)d_in[1];
    const float* dist    = (const float*)d_in[2];
    float* out = (float*)d_out;

    const int n_rays = in_sizes[2] / 128;   // distances is [N, 128]

    const int block = 64;                   // one wave per block
    const int grid  = (n_rays + 63) / 64;

    volrender_kernel<<<grid, block, 0, stream>>>(rgb, density, dist, out, n_rays);
}